// Round 3
// baseline (82.940 us; speedup 1.0000x reference)
//
#include <hip/hip_runtime.h>

// CondConv2d B=16,CIN=COUT=128,H=W=56,E=4,3x3,pad=1 fp32.
// 1) Fold routing into weights: Wm[b] = sum_e r[b,e] W[e]  (conv linear in W).
// 2) bf16 MFMA implicit GEMM per sample, fp32 accumulate.
// Round 3: latency-bound fix — K-split (2x waves, 7/SIMD), stage all ci once
// (1 barrier pair), linear-pointer A prefetch double-buffer.

typedef float  f32x4 __attribute__((ext_vector_type(4)));
typedef short  s16x8 __attribute__((ext_vector_type(8)));
typedef short  s16x4 __attribute__((ext_vector_type(4)));
typedef unsigned short u16x4 __attribute__((ext_vector_type(4)));

#define CIN  128
#define COUT 128
#define HH   56
#define WW   56
#define SP   (HH*WW)          // 3136
#define EW   147456           // per-expert weight elems
#define BW_  147456           // per-sample Wmix elems = [cc4][tap9][co128][ci_l32]
#define CIPAD 132             // LDS ci stride (264B: 8B-aligned, ~2-way banks)

static __device__ __forceinline__ unsigned short f2bf(float f) {
    unsigned u = __builtin_bit_cast(unsigned, f);
    return (unsigned short)((u + 0x7FFFu + ((u >> 16) & 1u)) >> 16);
}

// ---------------------------------------------------------------------------
// Phase 1: Wmix[b][cc][tap][co][ci_l] (bf16) = sum_e r[b,e]*W[e][co][cc*32+ci_l][tap]
// ---------------------------------------------------------------------------
__global__ __launch_bounds__(256) void mix_kernel(const float* __restrict__ W,
                                                  const float* __restrict__ r,
                                                  unsigned short* __restrict__ Wmix) {
    const int b = blockIdx.y;
    int o = blockIdx.x * 256 + threadIdx.x;          // [0, 147456)
    int ci_l = o & 31;
    int o2   = o >> 5;
    int co   = o2 & 127;
    int o3   = o2 >> 7;                              // [0, 36)
    int tap  = o3 % 9;
    int cc   = o3 / 9;
    int ci   = cc * 32 + ci_l;
    size_t src = ((size_t)co * CIN + ci) * 9 + tap;
    float acc = r[b*4+0] * W[src]
              + r[b*4+1] * W[src + 1*EW]
              + r[b*4+2] * W[src + 2*EW]
              + r[b*4+3] * W[src + 3*EW];
    Wmix[(size_t)b * BW_ + o] = f2bf(acc);
}

// ---------------------------------------------------------------------------
// Phase 2: block = (b, h, px-half). 256 thr, 4 waves = 2(co-half) x 2(K-half).
// Wave: 64co x 32px x K/2 -> 4x2 frags x 18 k-steps = 144 mfma_16x16x32_bf16.
// Stage 3 rows x 34 cols x 128 ci bf16 ONCE; A prefetched from global (linear
// pointer walk, double-buffered); K-halves reduced via LDS (reuse xs).
// ---------------------------------------------------------------------------
__global__ __launch_bounds__(256, 5) void conv_mfma(const float* __restrict__ x,
                                                    const unsigned short* __restrict__ Wmix,
                                                    float* __restrict__ out) {
    __shared__ __align__(16) unsigned short xs[3 * 34 * CIPAD];   // 26,928 B

    const int h    = blockIdx.x >> 1;
    const int pxh  = blockIdx.x & 1;                 // px half: w base = pxh*32
    const int b    = blockIdx.y;
    const int t    = threadIdx.x;
    const int lane = t & 63;
    const int wid  = t >> 6;
    const int wk   = wid >> 1;                       // K half (chunks 2*wk, 2*wk+1)
    const int wm   = wid & 1;                        // co half
    const int l15  = lane & 15;
    const int kg   = lane >> 4;
    const float* xb = x + (size_t)b * CIN * SP;

    // --- stage x: 3 rows x 34 cols x 128 ci (halo zero-padded), bf16 ---
    for (int s = t; s < 3*34*32; s += 256) {
        int col  = s % 34;
        int rest = s / 34;
        int q    = rest & 31;                        // ci quad
        int rr   = rest >> 5;                        // 0..2
        int row  = h - 1 + rr;
        int w    = pxh*32 + col - 1;
        u16x4 v = (u16x4)0;
        if ((unsigned)row < 56u && (unsigned)w < 56u) {
            const float* p = xb + (size_t)(q*4)*SP + row*56 + w;
            v[0] = f2bf(p[0]);
            v[1] = f2bf(p[SP]);
            v[2] = f2bf(p[2*SP]);
            v[3] = f2bf(p[3*SP]);
        }
        *(u16x4*)&xs[(rr*34 + col)*CIPAD + q*4] = v;
    }
    __syncthreads();

    f32x4 acc[4][2];
    #pragma unroll
    for (int mf = 0; mf < 4; ++mf)
        #pragma unroll
        for (int nf = 0; nf < 2; ++nf) acc[mf][nf] = (f32x4)0.f;

    // A base: 18 k-steps are contiguous slabs of 4096 elems (tap stride 4096,
    // chunk stride 9*4096) -> linear walk.
    const unsigned short* ab =
        Wmix + (size_t)b*BW_ + wk*(2*9*4096) + (wm*64 + l15)*32 + kg*8;

    s16x8 a[2][4];
    #pragma unroll
    for (int mf = 0; mf < 4; ++mf) a[0][mf] = *(const s16x8*)(ab + mf*512);

    #pragma unroll
    for (int cc_l = 0; cc_l < 2; ++cc_l) {
        const int ci0 = wk*64 + cc_l*32 + kg*8;      // LDS ci index for B frag
        #pragma unroll
        for (int tap = 0; tap < 9; ++tap) {
            const int s   = cc_l*9 + tap;            // compile-time
            const int kh  = tap / 3;
            const int kw  = tap % 3;
            // prefetch step s+1 (s==17 -> dummy re-read of step 0)
            const unsigned short* an = ab + (s == 17 ? 0 : (s+1)*4096);
            #pragma unroll
            for (int mf = 0; mf < 4; ++mf)
                a[(s+1)&1][mf] = *(const s16x8*)(an + mf*512);
            // B frags from LDS
            s16x8 bf[2];
            #pragma unroll
            for (int nf = 0; nf < 2; ++nf) {
                const unsigned short* ps =
                    &xs[(kh*34 + nf*16 + l15 + kw)*CIPAD + ci0];
                s16x4 lo = *(const s16x4*)ps;
                s16x4 hi = *(const s16x4*)(ps + 4);
                bf[nf] = __builtin_shufflevector(lo, hi, 0,1,2,3,4,5,6,7);
            }
            #pragma unroll
            for (int mf = 0; mf < 4; ++mf)
                #pragma unroll
                for (int nf = 0; nf < 2; ++nf)
                    acc[mf][nf] = __builtin_amdgcn_mfma_f32_16x16x32_bf16(
                        a[s&1][mf], bf[nf], acc[mf][nf], 0, 0, 0);
        }
    }

    // --- K-split reduction through LDS (reuse xs) ---
    __syncthreads();
    f32x4* red = (f32x4*)xs;                          // 1024 slots = 16 KB
    if (wk == 1) {
        #pragma unroll
        for (int mf = 0; mf < 4; ++mf)
            #pragma unroll
            for (int nf = 0; nf < 2; ++nf)
                red[((wm*4 + mf)*2 + nf)*64 + lane] = acc[mf][nf];
    }
    __syncthreads();
    if (wk == 0) {
        #pragma unroll
        for (int mf = 0; mf < 4; ++mf)
            #pragma unroll
            for (int nf = 0; nf < 2; ++nf) {
                f32x4 o = red[((wm*4 + mf)*2 + nf)*64 + lane];
                acc[mf][nf] += o;
            }
        #pragma unroll
        for (int nf = 0; nf < 2; ++nf) {
            int wout = pxh*32 + nf*16 + l15;
            if (wout < 56) {
                #pragma unroll
                for (int mf = 0; mf < 4; ++mf)
                    #pragma unroll
                    for (int rg = 0; rg < 4; ++rg) {
                        int co = wm*64 + mf*16 + kg*4 + rg;
                        out[(((size_t)b*COUT + co)*HH + h)*WW + wout] = acc[mf][nf][rg];
                    }
            }
        }
    }
}

extern "C" void kernel_launch(void* const* d_in, const int* in_sizes, int n_in,
                              void* d_out, int out_size, void* d_ws, size_t ws_size,
                              hipStream_t stream) {
    const float* x = (const float*)d_in[0];          // [16,128,56,56]
    const float* r = (const float*)d_in[1];          // [16,4]
    const float* W = (const float*)d_in[2];          // [4,128,128,3,3]
    float* outp = (float*)d_out;                     // [16,128,56,56]
    unsigned short* Wmix = (unsigned short*)d_ws;    // 16*147456 bf16 = 4.7 MB

    mix_kernel<<<dim3(576, 16), 256, 0, stream>>>(W, r, Wmix);
    conv_mfma <<<dim3(112, 16), 256, 0, stream>>>(x, Wmix, outp);
}